// Round 13
// baseline (234.132 us; speedup 1.0000x reference)
//
#include <hip/hip_runtime.h>
#include <hip/hip_fp16.h>

#define EPS 1e-8f
#define NU_MOL 1.5e-5f
#define NPB 512            // nodes per bucket (9-bit rl)
#define MAXNB 256          // max buckets (N <= 131072, 17-bit col pack)
#define NBP 256            // padded row stride of counts matrix
#define NBLK 1024          // edge-chunk blocks: chunk ~6250 -> per-bucket runs
                           // ~32 edges = 256B (R9 trend: bigger runs cut
                           // partial-line write inflation; 2048 gave 1.16x)
#define CMAX 6400          // max edges per block chunk (E <= 6.55M)
#define HB 5               // half-batch width for scatter phases B/C
#define NHB 5              // number of half-batches; KMAX = NHB*HB
#define KMAX 25            // ceil(CMAX/256)
#define CH 1536            // accum chunk entries (fp32x4 pl: 24KB)
#define KACC 3             // CH/512
#define SPLIT 6            // entry-slices per bucket in accum
#define NGRP 16            // block-groups for hierarchical scan
#define GRP 64             // rows per group; NGRP*GRP == NBLK

// ===================== helpers =====================

union U32H2 { unsigned u; __half2 h; };

__device__ inline unsigned packh2(float a, float b) {
    U32H2 x; x.h = __halves2half2(__float2half_rn(a), __float2half_rn(b));
    return x.u;
}
__device__ inline float2 unpackh2(unsigned u) {
    U32H2 x; x.u = u;
    return make_float2(__low2float(x.h), __high2float(x.h));
}

// Inline int64-vs-int32 detection (L2-broadcast reads, free).
__device__ inline int detect64(const void* eidx, int N) {
    const long long* ll = (const long long*)eidx;
    int is64 = 1;
    #pragma unroll
    for (int i = 0; i < 16; ++i) {
        long long v = ll[i];
        if (v < 0 || v >= (long long)N) is64 = 0;
    }
    return is64;
}

// ===================== common =====================

__global__ void detect_idx_dtype(const void* eidx, int N, int* flag) {
    const long long* ll = (const long long*)eidx;
    int is64 = 1;
    for (int i = 0; i < 16; ++i) {
        long long v = ll[i];
        if (v < 0 || v >= (long long)N) { is64 = 0; break; }
    }
    *flag = is64;
}

__global__ void finalize_kernel(const double* __restrict__ d,
                                const double* __restrict__ smooth_slots,
                                int N, int E, float* __restrict__ out)
{
    double smooth = 0.0;
    for (int i = 0; i < 64; ++i) smooth += smooth_slots[i];
    double dN = (double)N;
    double n_wall = d[5] > 1.0 ? d[5] : 1.0;
    double total = 1.0  * d[0] / (4.0 * dN)
                 + 0.1  * d[1] / dN
                 + 0.1  * d[2] / dN
                 + 0.05 * d[3] / dN
                 + 0.05 * d[4] / dN
                 + 0.05 * d[6] / n_wall
                 + 0.01 * smooth / (4.0 * (double)E)
                 + 0.02 * d[7] / n_wall;
    out[0] = (float)total;
}

// ===================== fast path =====================
// HARD RULES (all measured on this problem, this chip):
//  - LDS fp32 accumulation NOT viable in ANY form: plain atomicAdd = CAS loop
//    (R2, 200us); unsafeAtomicAdd = same 200us (R11). Counting sort with INT
//    rank-capture atomics + register run-sum is the accumulation mechanism.
//  - NO awaited global-atomic allocation >64 ops/address (R3: +90us).
//  - Pack-precompute for scatter: neutral-to-worse (R8).
//  - Fire-and-forget u32 atomics <=64-deep contention fine (R5).
//  - Big chunks cut partial-line write inflation (R9). Occupancy 32..67%
//    does NOT move scatter.
//  - Dense-random LDS: wider ops win; plane-split raised conflicts (R10).

// Pass 1: per-(block, bucket) counts; contiguous row writes. Folds the
// group-sum reduction in via fire-and-forget atomics into gsum[g][b].
// 4 per-wave parity histograms halve same-address serialization.
__global__ __launch_bounds__(256) void count_kernel(
    const void* __restrict__ eidx, int E, int N, int NB,
    unsigned* __restrict__ counts, unsigned* __restrict__ gsum)
{
    __shared__ unsigned hist[4][MAXNB];
    hist[0][threadIdx.x] = 0u;
    hist[1][threadIdx.x] = 0u;
    hist[2][threadIdx.x] = 0u;
    hist[3][threadIdx.x] = 0u;
    __syncthreads();
    const int w = (threadIdx.x >> 6) & 3;
    const int is64 = detect64(eidx, N);
    const long long* ll = (const long long*)eidx;
    const int* ii = (const int*)eidx;
    int chunk = (E + NBLK - 1) / NBLK;
    int s = blockIdx.x * chunk;
    int Cb = min(chunk, E - s);

    unsigned rr[KMAX];
    #pragma unroll
    for (int k = 0; k < KMAX; ++k) {
        int i = k * 256 + threadIdx.x;
        if (i < Cb) {
            int r = is64 ? (int)ll[s + i] : ii[s + i];
            rr[k] = (unsigned)min(max(r, 0), N - 1);
        } else rr[k] = 0xFFFFFFFFu;
    }
    #pragma unroll
    for (int k = 0; k < KMAX; ++k)
        if (rr[k] != 0xFFFFFFFFu)
            atomicAdd(&hist[w][rr[k] >> 9], 1u);
    __syncthreads();
    if (threadIdx.x < NB) {
        unsigned h = hist[0][threadIdx.x] + hist[1][threadIdx.x]
                   + hist[2][threadIdx.x] + hist[3][threadIdx.x];
        counts[(size_t)blockIdx.x * NBP + threadIdx.x] = h;
        if (h) atomicAdd(&gsum[(size_t)(blockIdx.x >> 6) * NBP + threadIdx.x], h);
    }
}

// Pass 2 (FUSED): every block redundantly recomputes the bucket-total scan
// from gsum (16KB load, registers + 256-wide shfl-scan), derives its own
// group's fold locally, then rewrites counts[blk][b] -> final global write
// offsets (old local_scan body). Block (0,0) writes base[]. Also zeroes the
// g[5][N] array (removes 2MB from the host memset). Replaces the scan_base
// dispatch entirely (~1 launch boundary saved).
__global__ __launch_bounds__(256) void scanlocal_kernel(
    unsigned* __restrict__ counts, const unsigned* __restrict__ gsum,
    unsigned* __restrict__ base, float* __restrict__ g, int N, int NB)
{
    __shared__ unsigned runstart[NBP];
    __shared__ unsigned segs[4][64];
    __shared__ unsigned wt[4];

    const int t = threadIdx.x;
    const int gidx = blockIdx.x;           // group handled by this block
    const int lane = t & 63, wv = t >> 6;

    // global bucket-total scan (redundant per block; thread t owns bucket t)
    unsigned vg[NGRP];
    unsigned total = 0, pref = 0;
    #pragma unroll
    for (int q = 0; q < NGRP; ++q) {
        vg[q] = gsum[(size_t)q * NBP + t];
        if (q < gidx) pref += vg[q];
        total += vg[q];
    }
    unsigned x = total;
    #pragma unroll
    for (int off = 1; off < 64; off <<= 1) {
        unsigned y = (unsigned)__shfl_up((int)x, off, 64);
        if (lane >= off) x += y;
    }
    if (lane == 63) wt[wv] = x;
    __syncthreads();
    unsigned wadd = 0;
    for (int w2 = 0; w2 < wv; ++w2) wadd += wt[w2];
    unsigned incl = x + wadd;
    unsigned ex = incl - total;
    runstart[t] = ex + pref;
    if (gidx == 0 && blockIdx.y == 0) {
        if (t < NB) base[t] = ex;
        if (t == 255) base[NB] = incl;     // = E (buckets >= NB are empty)
    }
    __syncthreads();

    // zero g[5][N] slice (was part of host memset)
    {
        size_t totf = (size_t)5 * N;
        int nblk = gridDim.x * gridDim.y;
        int bid = blockIdx.y * gridDim.x + blockIdx.x;
        size_t per = (totf + nblk - 1) / nblk;
        size_t s0 = (size_t)bid * per;
        size_t e0 = s0 + per; if (e0 > totf) e0 = totf;
        for (size_t i = s0 + t; i < e0; i += 256) g[i] = 0.f;
    }

    // within-group scan: counts[blk][b] -> final global write offset
    int b0 = blockIdx.y * 64;
    int j = t & 63, seg = t >> 6;
    int b = b0 + j;
    unsigned v[16];
    unsigned ssum = 0;
    if (b < NB) {
        #pragma unroll
        for (int k = 0; k < 16; ++k) {
            int row = gidx * GRP + seg * 16 + k;
            v[k] = counts[(size_t)row * NBP + b];
            ssum += v[k];
        }
    }
    segs[seg][j] = ssum;
    __syncthreads();
    if (b < NB) {
        unsigned carry = runstart[b];
        for (int s_ = 0; s_ < seg; ++s_) carry += segs[s_][j];
        #pragma unroll
        for (int k = 0; k < 16; ++k) {
            int row = gidx * GRP + seg * 16 + k;
            counts[(size_t)row * NBP + b] = carry;
            carry += v[k];
        }
    }
}

// Pass 3: streaming scatter (R9 structure, bigger chunk). Rank captured from
// Phase-A histogram atomic -> Phase B atomic-free. B/C in 5x5 half-batches.
__global__ __launch_bounds__(256) void scatter_kernel(
    const void* __restrict__ eidx, const float2* __restrict__ eattr,
    int E, int N, int NB,
    const unsigned* __restrict__ localoff /* scanned counts [blk][NBP] */,
    uint2* __restrict__ vals)
{
    __shared__ unsigned hist[2][MAXNB];   // per-parity histograms (preserved)
    __shared__ unsigned cur[MAXNB];       // merged exclusive scan
    __shared__ unsigned gb2[MAXNB];
    __shared__ uint2 pl[CMAX];            // 51.2 KB staged payloads (8B: 2-way)
    __shared__ unsigned char bb[CMAX];    // 6.4 KB bucket ids
    __shared__ unsigned wt[4];

    const int t = threadIdx.x;
    const int blk = blockIdx.x;
    const int lane = t & 63, wv = t >> 6;
    const int w = wv & 1;
    const int is64 = detect64(eidx, N);
    const long long* ll = (const long long*)eidx;
    const int* ii = (const int*)eidx;
    const int chunk = (E + NBLK - 1) / NBLK;
    const int s = blk * chunk;
    const int Cb = min(chunk, E - s);

    hist[0][t] = 0u;
    hist[1][t] = 0u;
    __syncthreads();

    // Phase A: batched row loads -> histogram atomics w/ rank capture.
    unsigned rr[KMAX], rk[KMAX];
    #pragma unroll
    for (int k = 0; k < KMAX; ++k) {
        int i = k * 256 + t;
        if (i < Cb) {
            int r = is64 ? (int)ll[s + i] : ii[s + i];
            rr[k] = (unsigned)min(max(r, 0), N - 1);
        } else rr[k] = 0xFFFFFFFFu;
    }
    #pragma unroll
    for (int k = 0; k < KMAX; ++k)
        if (rr[k] != 0xFFFFFFFFu)
            rk[k] = atomicAdd(&hist[w][rr[k] >> 9], 1u);
    if (t < NB) gb2[t] = localoff[(size_t)blk * NBP + t];
    __syncthreads();

    // merge + exclusive shfl-scan of 256 bins (hist[0]/hist[1] preserved)
    unsigned h = hist[0][t] + hist[1][t];
    unsigned x = h;
    #pragma unroll
    for (int off = 1; off < 64; off <<= 1) {
        unsigned y = (unsigned)__shfl_up((int)x, off, 64);
        if (lane >= off) x += y;
    }
    if (lane == 63) wt[wv] = x;
    __syncthreads();
    unsigned wadd = 0;
    for (int w2 = 0; w2 < wv; ++w2) wadd += wt[w2];
    unsigned ex = x + wadd - h;
    cur[t] = ex;
    __syncthreads();
    if (t < NB) gb2[t] -= cur[t];

    // Phase B: half-batched col+attr loads, then atomic-free staged writes.
    #pragma unroll
    for (int hb = 0; hb < NHB; ++hb) {
        const int k0 = hb * HB;
        int cc[HB]; float2 dd[HB];
        #pragma unroll
        for (int k = k0; k < k0 + HB; ++k) {
            int i = k * 256 + t;
            if (i < Cb) {
                int e = s + i;
                cc[k - k0] = is64 ? (int)ll[(long long)E + e] : ii[E + e];
                dd[k - k0] = eattr[e];
            }
        }
        #pragma unroll
        for (int k = k0; k < k0 + HB; ++k) {
            int i = k * 256 + t;
            if (i < Cb) {
                unsigned r = rr[k];
                unsigned b = r >> 9;
                unsigned rl = r & (NPB - 1);
                int c = min(max(cc[k - k0], 0), N - 1);
                unsigned slot = cur[b] + (w ? hist[0][b] : 0u) + rk[k];
                pl[slot] = make_uint2((unsigned)c | (rl << 17),
                                      packh2(dd[k - k0].x, dd[k - k0].y));
                bb[slot] = (unsigned char)b;
            }
        }
    }
    __syncthreads();

    // Phase C: half-batched staged reads -> coalesced global stores.
    #pragma unroll
    for (int hb = 0; hb < NHB; ++hb) {
        const int k0 = hb * HB;
        uint2 op[HB]; unsigned ob[HB];
        #pragma unroll
        for (int k = k0; k < k0 + HB; ++k) {
            int p = k * 256 + t;
            if (p < Cb) { op[k - k0] = pl[p]; ob[k - k0] = (unsigned)bb[p]; }
        }
        #pragma unroll
        for (int k = k0; k < k0 + HB; ++k) {
            int p = k * 256 + t;
            if (p < Cb) vals[gb2[ob[k - k0]] + (unsigned)p] = op[k - k0];
        }
    }
}

// Pass 4: gather + physics + in-LDS counting sort + register run-sum.
// INT histogram atomics only; fp32x4 pl staging (R9); raw v_rcp_f32 (R7).
__global__ __launch_bounds__(512) void accum_kernel(
    const uint2* __restrict__ vals, const unsigned* __restrict__ base,
    const float4* __restrict__ pred, int N,
    float* __restrict__ g /* [5][N] */, double* __restrict__ smooth_slots)
{
    __shared__ float4 pl[CH];          // 24 KB sorted fp32x4 physics
    __shared__ uint2 ph[NPB];          // 4 KB fp16 pred of bucket rows
    __shared__ unsigned hist[NPB];     // 2 KB
    __shared__ unsigned cur[NPB];      // 2 KB
    __shared__ unsigned wt[8];
    __shared__ double sm[8];

    const int b = blockIdx.x;
    const int t = threadIdx.x;
    const int wv = t >> 6, lane = t & 63;
    const int n0 = b * NPB;

    {   // stage bucket's pred rows as fp16
        int n = n0 + t;
        float4 p = (n < N) ? pred[n] : make_float4(0.f, 0.f, 0.f, 0.f);
        ph[t] = make_uint2(packh2(p.x, p.y), packh2(p.z, p.w));
    }

    unsigned s0 = base[b], e0 = base[b + 1];
    unsigned len = e0 - s0;
    unsigned s = s0 + (unsigned)(((unsigned long long)len * blockIdx.y) / SPLIT);
    unsigned e = s0 + (unsigned)(((unsigned long long)len * (blockIdx.y + 1)) / SPLIT);

    float cnt = 0, sdiv = 0, smx = 0, smy = 0, sstr = 0;
    double smooth = 0.0;

    for (unsigned cs = s; cs < e; cs += CH) {
        const int n = (int)min((unsigned)CH, e - cs);
        hist[t] = 0u;
        __syncthreads();

        uint2 vv[KACC]; unsigned rk2[KACC]; float4 pcc[KACC];
        #pragma unroll
        for (int k = 0; k < KACC; ++k) {
            int i = k * 512 + t;
            if (i < n) vv[k] = vals[cs + i];
            else vv[k].x = 0xFFFFFFFFu;
        }
        #pragma unroll
        for (int k = 0; k < KACC; ++k) {
            int i = k * 512 + t;
            if (i < n) {
                rk2[k] = atomicAdd(&hist[(vv[k].x >> 17) & (NPB - 1)], 1u);
                pcc[k] = pred[vv[k].x & 0x1FFFFu];
            }
        }
        __syncthreads();

        unsigned v = hist[t];
        unsigned x = v;
        #pragma unroll
        for (int off = 1; off < 64; off <<= 1) {
            unsigned y = (unsigned)__shfl_up((int)x, off, 64);
            if (lane >= off) x += y;
        }
        if (lane == 63) wt[wv] = x;
        __syncthreads();
        unsigned wadd = 0;
        for (int w = 0; w < wv; ++w) wadd += wt[w];
        unsigned incl = x + wadd;
        unsigned ex0 = incl - v;
        cur[t] = ex0;
        cnt += (float)v;
        __syncthreads();

        #pragma unroll
        for (int k = 0; k < KACC; ++k) {
            int i = k * 512 + t;
            if (i >= n) continue;
            unsigned pk = vv[k].x;
            unsigned rl = (pk >> 17) & (NPB - 1);
            float2 dxy = unpackh2(vv[k].y);
            float4 pc = pcc[k];
            uint2 pru = ph[rl];
            float2 pxy = unpackh2(pru.x);
            float2 pzw = unpackh2(pru.y);
            float du = pc.x - pxy.x, dv = pc.y - pxy.y;
            float dp = pc.z - pzw.x, dn = pc.w - pzw.y;
            float rx  = __builtin_amdgcn_rcpf(dxy.x + EPS);
            float ry  = __builtin_amdgcn_rcpf(dxy.y + EPS);
            float rx2 = __builtin_amdgcn_rcpf(dxy.x * dxy.x + EPS);
            float ry2 = __builtin_amdgcn_rcpf(dxy.y * dxy.y + EPS);
            float du_dx = du * rx, du_dy = du * ry;
            float dv_dx = dv * rx, dv_dy = dv * ry;
            float nu_eff = NU_MOL + pzw.y;
            float sh = du_dy + dv_dx;
            float div_e = du_dx + dv_dy;
            float mx_e  = dp * rx + nu_eff * du * rx2;
            float my_e  = dp * ry + nu_eff * dv * ry2;
            float str_e = 2.0f * (du_dx * du_dx + dv_dy * dv_dy) + sh * sh;
            pl[cur[rl] + rk2[k]] = make_float4(div_e, mx_e, my_e, str_e);
            smooth += (double)(du * du + dv * dv + dp * dp + dn * dn);
        }
        __syncthreads();

        for (unsigned i = ex0; i < incl; ++i) {
            float4 pv = pl[i];
            sdiv += pv.x;
            smx  += pv.y;
            smy  += pv.z;
            sstr += pv.w;
        }
        __syncthreads();
    }

    {
        int n = n0 + t;
        if (n < N) {
            atomicAdd(&g[0 * (size_t)N + n], cnt);
            atomicAdd(&g[1 * (size_t)N + n], sdiv);
            atomicAdd(&g[2 * (size_t)N + n], smx);
            atomicAdd(&g[3 * (size_t)N + n], smy);
            atomicAdd(&g[4 * (size_t)N + n], sstr);
        }
    }

    for (int off = 32; off > 0; off >>= 1)
        smooth += __shfl_down(smooth, off);
    if (lane == 0) sm[wv] = smooth;
    __syncthreads();
    if (t == 0) {
        double tot = 0;
        #pragma unroll
        for (int w = 0; w < 8; ++w) tot += sm[w];
        atomicAdd(&smooth_slots[(b * SPLIT + blockIdx.y) & 63], tot);
    }
}

// Pass 5: node losses from g[5][N].
__global__ __launch_bounds__(256) void node_final_kernel(
    const float* __restrict__ g, const float4* __restrict__ pred,
    const float4* __restrict__ tgt, const unsigned char* __restrict__ wall,
    int N, double* __restrict__ d)
{
    int i = blockIdx.x * 256 + threadIdx.x;
    double v0 = 0, v1 = 0, v2 = 0, v3 = 0, v4 = 0, v5 = 0, v6 = 0, v7 = 0;
    if (i < N) {
        float cnt = g[0 * (size_t)N + i];
        float inv = 1.0f / fmaxf(cnt, 1.0f);
        float div = g[1 * (size_t)N + i] * inv;
        float mx  = g[2 * (size_t)N + i] * inv;
        float my  = g[3 * (size_t)N + i] * inv;
        float sn  = g[4 * (size_t)N + i] * inv;
        float4 p = pred[i];
        float4 tg = tgt[i];
        float prod = p.w * sn;
        float m = wall[i] ? 1.0f : 0.0f;
        float e0 = p.x - tg.x, e1 = p.y - tg.y, e2 = p.z - tg.z, e3 = p.w - tg.w;
        float uv = p.x * p.x + p.y * p.y;
        v0 = (double)(e0 * e0 + e1 * e1 + e2 * e2 + e3 * e3);
        v1 = (double)div * (double)div;
        v2 = (double)mx * (double)mx + (double)my * (double)my;
        v3 = (double)prod * (double)prod;
        v4 = (double)p.w * (double)p.w;
        v5 = (double)m;
        v6 = (double)(m * uv);
        v7 = (double)(m * (uv + p.w * p.w));
    }
    for (int off = 32; off > 0; off >>= 1) {
        v0 += __shfl_down(v0, off); v1 += __shfl_down(v1, off);
        v2 += __shfl_down(v2, off); v3 += __shfl_down(v3, off);
        v4 += __shfl_down(v4, off); v5 += __shfl_down(v5, off);
        v6 += __shfl_down(v6, off); v7 += __shfl_down(v7, off);
    }
    __shared__ double sm[4][8];
    int lane = threadIdx.x & 63, wv = threadIdx.x >> 6;
    if (lane == 0) {
        sm[wv][0] = v0; sm[wv][1] = v1; sm[wv][2] = v2; sm[wv][3] = v3;
        sm[wv][4] = v4; sm[wv][5] = v5; sm[wv][6] = v6; sm[wv][7] = v7;
    }
    __syncthreads();
    if (threadIdx.x < 8) {
        int q = threadIdx.x;
        atomicAdd(&d[q], sm[0][q] + sm[1][q] + sm[2][q] + sm[3][q]);
    }
}

// ===================== fallback path (R1-style, known-correct) =====================

__global__ __launch_bounds__(256) void edge_kernel(
    const void* __restrict__ eidx, const float2* __restrict__ eattr,
    const float4* __restrict__ pred, int E, int N, const int* __restrict__ flag,
    float* __restrict__ a_cnt, float* __restrict__ a_div,
    float* __restrict__ a_mx, float* __restrict__ a_my,
    float* __restrict__ a_str, double* __restrict__ smooth_slots)
{
    const int is64 = *flag;
    const long long* ll = (const long long*)eidx;
    const int* ii = (const int*)eidx;
    double smooth = 0.0;
    const int stride = gridDim.x * blockDim.x;
    for (int e = blockIdx.x * blockDim.x + threadIdx.x; e < E; e += stride) {
        int row, col;
        if (is64) { row = (int)ll[e]; col = (int)ll[(long long)E + e]; }
        else      { row = ii[e];      col = ii[E + e]; }
        row = min(max(row, 0), N - 1);
        col = min(max(col, 0), N - 1);
        float2 dxy = eattr[e];
        float4 pr = pred[row];
        float4 pc = pred[col];
        float du = pc.x - pr.x, dv = pc.y - pr.y;
        float dp = pc.z - pr.z, dn = pc.w - pr.w;
        float rx  = 1.0f / (dxy.x + EPS);
        float ry  = 1.0f / (dxy.y + EPS);
        float rx2 = 1.0f / (dxy.x * dxy.x + EPS);
        float ry2 = 1.0f / (dxy.y * dxy.y + EPS);
        float du_dx = du * rx, du_dy = du * ry;
        float dv_dx = dv * rx, dv_dy = dv * ry;
        float nu_eff = NU_MOL + pr.w;
        atomicAdd(&a_cnt[row], 1.0f);
        atomicAdd(&a_div[row], du_dx + dv_dy);
        atomicAdd(&a_mx[row], dp * rx + nu_eff * du * rx2);
        atomicAdd(&a_my[row], dp * ry + nu_eff * dv * ry2);
        float sh = du_dy + dv_dx;
        atomicAdd(&a_str[row], 2.0f * (du_dx * du_dx + dv_dy * dv_dy) + sh * sh);
        smooth += (double)(du * du + dv * dv + dp * dp + dn * dn);
    }
    for (int off = 32; off > 0; off >>= 1)
        smooth += __shfl_down(smooth, off);
    __shared__ double sm[4];
    int lane = threadIdx.x & 63, wv = threadIdx.x >> 6;
    if (lane == 0) sm[wv] = smooth;
    __syncthreads();
    if (threadIdx.x == 0)
        atomicAdd(&smooth_slots[blockIdx.x & 63], sm[0] + sm[1] + sm[2] + sm[3]);
}

__global__ __launch_bounds__(256) void node_kernel(
    const float4* __restrict__ pred, const float4* __restrict__ tgt,
    const unsigned char* __restrict__ wall, int N,
    const float* __restrict__ a_cnt, const float* __restrict__ a_div,
    const float* __restrict__ a_mx, const float* __restrict__ a_my,
    const float* __restrict__ a_str, double* __restrict__ d)
{
    int i = blockIdx.x * blockDim.x + threadIdx.x;
    double v0 = 0, v1 = 0, v2 = 0, v3 = 0, v4 = 0, v5 = 0, v6 = 0, v7 = 0;
    if (i < N) {
        float4 p = pred[i];
        float4 t = tgt[i];
        float inv = 1.0f / fmaxf(a_cnt[i], 1.0f);
        float div = a_div[i] * inv;
        float mx = a_mx[i] * inv, my = a_my[i] * inv;
        float sn = a_str[i] * inv;
        float prod = p.w * sn;
        float m = wall[i] ? 1.0f : 0.0f;
        float e0 = p.x - t.x, e1 = p.y - t.y, e2 = p.z - t.z, e3 = p.w - t.w;
        float uv = p.x * p.x + p.y * p.y;
        v0 = (double)(e0 * e0 + e1 * e1 + e2 * e2 + e3 * e3);
        v1 = (double)div * (double)div;
        v2 = (double)mx * (double)mx + (double)my * (double)my;
        v3 = (double)prod * (double)prod;
        v4 = (double)p.w * (double)p.w;
        v5 = (double)m;
        v6 = (double)(m * uv);
        v7 = (double)(m * (uv + p.w * p.w));
    }
    for (int off = 32; off > 0; off >>= 1) {
        v0 += __shfl_down(v0, off); v1 += __shfl_down(v1, off);
        v2 += __shfl_down(v2, off); v3 += __shfl_down(v3, off);
        v4 += __shfl_down(v4, off); v5 += __shfl_down(v5, off);
        v6 += __shfl_down(v6, off); v7 += __shfl_down(v7, off);
    }
    __shared__ double sm[4][8];
    int lane = threadIdx.x & 63, wv = threadIdx.x >> 6;
    if (lane == 0) {
        sm[wv][0] = v0; sm[wv][1] = v1; sm[wv][2] = v2; sm[wv][3] = v3;
        sm[wv][4] = v4; sm[wv][5] = v5; sm[wv][6] = v6; sm[wv][7] = v7;
    }
    __syncthreads();
    if (threadIdx.x < 8) {
        int q = threadIdx.x;
        atomicAdd(&d[q], sm[0][q] + sm[1][q] + sm[2][q] + sm[3][q]);
    }
}

// ===================== launch =====================

extern "C" void kernel_launch(void* const* d_in, const int* in_sizes, int n_in,
                              void* d_out, int out_size, void* d_ws, size_t ws_size,
                              hipStream_t stream) {
    const float4* pred = (const float4*)d_in[0];
    const float4* tgt  = (const float4*)d_in[1];
    const float2* eattr = (const float2*)d_in[2];
    const void* eidx = d_in[3];
    const unsigned char* wall = (const unsigned char*)d_in[4];
    int N = in_sizes[0] / 4;
    int E = in_sizes[2] / 2;
    int NB = (N + NPB - 1) / NPB;
    int chunk = (E + NBLK - 1) / NBLK;
    int ntiles = (NB + 63) / 64;

    char* ws = (char*)d_ws;
    double* d = (double*)ws;                 // 8 scalars
    double* smooth_slots = d + 8;            // 64 slots
    int* flag = (int*)(ws + 576);

    size_t off = 1024;
    unsigned* gsum   = (unsigned*)(ws + off); off += (size_t)NGRP * NBP * 4; // zeroed
    size_t zbytes = off;                      // only header + gsum (~17KB)
    float* g        = (float*)(ws + off);     off += (size_t)5 * N * 4;  // zeroed by scanlocal
    unsigned* counts = (unsigned*)(ws + off); off += (size_t)NBLK * NBP * 4;
    unsigned* base   = (unsigned*)(ws + off); off += (size_t)(NB + 1) * 4;
    off = (off + 15) & ~(size_t)15;
    uint2* vals      = (uint2*)(ws + off);    off += (size_t)E * 8;
    size_t need_fast = off;

    bool fast = (NB <= MAXNB) && (N <= 131072) && (chunk <= CMAX) &&
                (ws_size >= need_fast);

    if (fast) {
        hipMemsetAsync(d_ws, 0, zbytes, stream);
        count_kernel<<<NBLK, 256, 0, stream>>>(eidx, E, N, NB, counts, gsum);
        scanlocal_kernel<<<dim3(NGRP, ntiles), 256, 0, stream>>>(counts, gsum,
                                                                 base, g, N, NB);
        scatter_kernel<<<NBLK, 256, 0, stream>>>(eidx, eattr, E, N, NB,
                                                 counts, vals);
        accum_kernel<<<dim3(NB, SPLIT), 512, 0, stream>>>(vals, base, pred, N,
                                                          g, smooth_slots);
        node_final_kernel<<<(N + 255) / 256, 256, 0, stream>>>(g, pred, tgt, wall,
                                                               N, d);
        finalize_kernel<<<1, 1, 0, stream>>>(d, smooth_slots, N, E, (float*)d_out);
    } else {
        float* arrays = (float*)(ws + 1024);
        float* a_cnt = arrays + (size_t)0 * N;
        float* a_div = arrays + (size_t)1 * N;
        float* a_mx  = arrays + (size_t)2 * N;
        float* a_my  = arrays + (size_t)3 * N;
        float* a_str = arrays + (size_t)4 * N;
        size_t zb = 1024 + (size_t)5 * N * sizeof(float);
        hipMemsetAsync(d_ws, 0, zb, stream);
        detect_idx_dtype<<<1, 1, 0, stream>>>(eidx, N, flag);
        edge_kernel<<<4096, 256, 0, stream>>>(eidx, eattr, pred, E, N, flag,
                                              a_cnt, a_div, a_mx, a_my, a_str,
                                              smooth_slots);
        node_kernel<<<(N + 255) / 256, 256, 0, stream>>>(pred, tgt, wall, N,
                                                         a_cnt, a_div, a_mx, a_my,
                                                         a_str, d);
        finalize_kernel<<<1, 1, 0, stream>>>(d, smooth_slots, N, E, (float*)d_out);
    }
}

// Round 14
// 225.720 us; speedup vs baseline: 1.0373x; 1.0373x over previous
//
#include <hip/hip_runtime.h>
#include <hip/hip_fp16.h>

#define EPS 1e-8f
#define NU_MOL 1.5e-5f
#define NPB 512            // nodes per bucket (9-bit rl)
#define MAXNB 256          // max buckets (N <= 131072, 17-bit col pack)
#define NBP 256            // padded row stride of counts matrix
#define NBLK 2048          // OPTIMUM (measured): 4096 -> 1.34x write inflation
                           // (R8); 1024 -> 17% occupancy cliff, scatter +4.5us
                           // (R13). 2048 = 128B runs, 1.16x, 4 blocks/CU (R9).
#define CMAX 3328          // max edges per block chunk (E <= 6.81M)
#define KMAX 13            // ceil(CMAX/256)
#define HB 7               // half-batch width for scatter phases B/C (VGPR cap)
#define CH 1536            // accum chunk entries (fp32x4 pl: 24KB)
#define KACC 3             // CH/512
#define SPLIT 6            // entry-slices per bucket in accum
#define NGRP 32            // block-groups for hierarchical scan
#define GRP 64             // rows per group; NGRP*GRP == NBLK

// ===================== helpers =====================

union U32H2 { unsigned u; __half2 h; };

__device__ inline unsigned packh2(float a, float b) {
    U32H2 x; x.h = __halves2half2(__float2half_rn(a), __float2half_rn(b));
    return x.u;
}
__device__ inline float2 unpackh2(unsigned u) {
    U32H2 x; x.u = u;
    return make_float2(__low2float(x.h), __high2float(x.h));
}

// Inline int64-vs-int32 detection (L2-broadcast reads, free).
__device__ inline int detect64(const void* eidx, int N) {
    const long long* ll = (const long long*)eidx;
    int is64 = 1;
    #pragma unroll
    for (int i = 0; i < 16; ++i) {
        long long v = ll[i];
        if (v < 0 || v >= (long long)N) is64 = 0;
    }
    return is64;
}

// ===================== common =====================

__global__ void detect_idx_dtype(const void* eidx, int N, int* flag) {
    const long long* ll = (const long long*)eidx;
    int is64 = 1;
    for (int i = 0; i < 16; ++i) {
        long long v = ll[i];
        if (v < 0 || v >= (long long)N) { is64 = 0; break; }
    }
    *flag = is64;
}

__global__ void finalize_kernel(const double* __restrict__ d,
                                const double* __restrict__ smooth_slots,
                                int N, int E, float* __restrict__ out)
{
    double smooth = 0.0;
    for (int i = 0; i < 64; ++i) smooth += smooth_slots[i];
    double dN = (double)N;
    double n_wall = d[5] > 1.0 ? d[5] : 1.0;
    double total = 1.0  * d[0] / (4.0 * dN)
                 + 0.1  * d[1] / dN
                 + 0.1  * d[2] / dN
                 + 0.05 * d[3] / dN
                 + 0.05 * d[4] / dN
                 + 0.05 * d[6] / n_wall
                 + 0.01 * smooth / (4.0 * (double)E)
                 + 0.02 * d[7] / n_wall;
    out[0] = (float)total;
}

// ===================== fast path =====================
// HARD RULES (all measured on this problem, this chip):
//  - LDS fp32 accumulation NOT viable in ANY form: plain atomicAdd = CAS loop
//    (R2, 200us); unsafeAtomicAdd = same 200us (R11). Counting sort with INT
//    rank-capture atomics + register run-sum is the accumulation mechanism.
//  - NO awaited global-atomic allocation >64 ops/address (R3: +90us).
//  - Pack-precompute for scatter: neutral-to-worse (R8).
//  - Fire-and-forget u32 atomics <=64-deep contention fine (R5).
//  - Scatter chunk size: NBLK=2048 optimum (R8/R9/R13 sweep). Occupancy flat
//    32..67% but cliffs at ~17% (R13).
//  - Dense-random LDS: wider ops win; plane-split raised conflicts (R10).

// Pass 1: per-(block, bucket) counts; contiguous row writes. Folds the
// group-sum reduction in via fire-and-forget atomics into gsum[g][b].
// 4 per-wave parity histograms halve same-address serialization.
__global__ __launch_bounds__(256) void count_kernel(
    const void* __restrict__ eidx, int E, int N, int NB,
    unsigned* __restrict__ counts, unsigned* __restrict__ gsum)
{
    __shared__ unsigned hist[4][MAXNB];
    hist[0][threadIdx.x] = 0u;
    hist[1][threadIdx.x] = 0u;
    hist[2][threadIdx.x] = 0u;
    hist[3][threadIdx.x] = 0u;
    __syncthreads();
    const int w = (threadIdx.x >> 6) & 3;
    const int is64 = detect64(eidx, N);
    const long long* ll = (const long long*)eidx;
    const int* ii = (const int*)eidx;
    int chunk = (E + NBLK - 1) / NBLK;
    int s = blockIdx.x * chunk;
    int Cb = min(chunk, E - s);

    unsigned rr[KMAX];
    #pragma unroll
    for (int k = 0; k < KMAX; ++k) {
        int i = k * 256 + threadIdx.x;
        if (i < Cb) {
            int r = is64 ? (int)ll[s + i] : ii[s + i];
            rr[k] = (unsigned)min(max(r, 0), N - 1);
        } else rr[k] = 0xFFFFFFFFu;
    }
    #pragma unroll
    for (int k = 0; k < KMAX; ++k)
        if (rr[k] != 0xFFFFFFFFu)
            atomicAdd(&hist[w][rr[k] >> 9], 1u);
    __syncthreads();
    if (threadIdx.x < NB) {
        unsigned h = hist[0][threadIdx.x] + hist[1][threadIdx.x]
                   + hist[2][threadIdx.x] + hist[3][threadIdx.x];
        counts[(size_t)blockIdx.x * NBP + threadIdx.x] = h;
        if (h) atomicAdd(&gsum[(size_t)(blockIdx.x >> 6) * NBP + threadIdx.x], h);
    }
}

// Pass 2 (FUSED, verified R13): every block redundantly recomputes the
// bucket-total scan from gsum (32KB L2 load, registers + 256-wide shfl-scan),
// derives its own group's fold locally, then rewrites counts[blk][b] ->
// final global write offsets. Block (0,0) writes base[]. Also zeroes g[5][N]
// (removes 2MB from the host memset). Replaces the scan_base dispatch.
__global__ __launch_bounds__(256) void scanlocal_kernel(
    unsigned* __restrict__ counts, const unsigned* __restrict__ gsum,
    unsigned* __restrict__ base, float* __restrict__ g, int N, int NB)
{
    __shared__ unsigned runstart[NBP];
    __shared__ unsigned segs[4][64];
    __shared__ unsigned wt[4];

    const int t = threadIdx.x;
    const int gidx = blockIdx.x;           // group handled by this block
    const int lane = t & 63, wv = t >> 6;

    // global bucket-total scan (redundant per block; thread t owns bucket t)
    unsigned vg[NGRP];
    unsigned total = 0, pref = 0;
    #pragma unroll
    for (int q = 0; q < NGRP; ++q) {
        vg[q] = gsum[(size_t)q * NBP + t];
        if (q < gidx) pref += vg[q];
        total += vg[q];
    }
    unsigned x = total;
    #pragma unroll
    for (int off = 1; off < 64; off <<= 1) {
        unsigned y = (unsigned)__shfl_up((int)x, off, 64);
        if (lane >= off) x += y;
    }
    if (lane == 63) wt[wv] = x;
    __syncthreads();
    unsigned wadd = 0;
    for (int w2 = 0; w2 < wv; ++w2) wadd += wt[w2];
    unsigned incl = x + wadd;
    unsigned ex = incl - total;
    runstart[t] = ex + pref;
    if (gidx == 0 && blockIdx.y == 0) {
        if (t < NB) base[t] = ex;
        if (t == 255) base[NB] = incl;     // = E (buckets >= NB are empty)
    }
    __syncthreads();

    // zero g[5][N] slice (was part of host memset)
    {
        size_t totf = (size_t)5 * N;
        int nblk = gridDim.x * gridDim.y;
        int bid = blockIdx.y * gridDim.x + blockIdx.x;
        size_t per = (totf + nblk - 1) / nblk;
        size_t s0 = (size_t)bid * per;
        size_t e0 = s0 + per; if (e0 > totf) e0 = totf;
        for (size_t i = s0 + t; i < e0; i += 256) g[i] = 0.f;
    }

    // within-group scan: counts[blk][b] -> final global write offset
    int b0 = blockIdx.y * 64;
    int j = t & 63, seg = t >> 6;
    int b = b0 + j;
    unsigned v[16];
    unsigned ssum = 0;
    if (b < NB) {
        #pragma unroll
        for (int k = 0; k < 16; ++k) {
            int row = gidx * GRP + seg * 16 + k;
            v[k] = counts[(size_t)row * NBP + b];
            ssum += v[k];
        }
    }
    segs[seg][j] = ssum;
    __syncthreads();
    if (b < NB) {
        unsigned carry = runstart[b];
        for (int s_ = 0; s_ < seg; ++s_) carry += segs[s_][j];
        #pragma unroll
        for (int k = 0; k < 16; ++k) {
            int row = gidx * GRP + seg * 16 + k;
            counts[(size_t)row * NBP + b] = carry;
            carry += v[k];
        }
    }
}

// Pass 3: streaming scatter (verified R9/R12). Rank captured from Phase-A
// histogram atomic -> Phase B atomic-free. Phases B/C in 7-wide half-batches.
__global__ __launch_bounds__(256) void scatter_kernel(
    const void* __restrict__ eidx, const float2* __restrict__ eattr,
    int E, int N, int NB,
    const unsigned* __restrict__ localoff /* scanned counts [blk][NBP] */,
    uint2* __restrict__ vals)
{
    __shared__ unsigned hist[2][MAXNB];   // per-parity histograms (preserved)
    __shared__ unsigned cur[MAXNB];       // merged exclusive scan
    __shared__ unsigned gb2[MAXNB];
    __shared__ uint2 pl[CMAX];            // 26.6 KB staged payloads (8B: 2-way)
    __shared__ unsigned char bb[CMAX];    // 3.3 KB bucket ids
    __shared__ unsigned wt[4];

    const int t = threadIdx.x;
    const int blk = blockIdx.x;
    const int lane = t & 63, wv = t >> 6;
    const int w = wv & 1;
    const int is64 = detect64(eidx, N);
    const long long* ll = (const long long*)eidx;
    const int* ii = (const int*)eidx;
    const int chunk = (E + NBLK - 1) / NBLK;
    const int s = blk * chunk;
    const int Cb = min(chunk, E - s);

    hist[0][t] = 0u;
    hist[1][t] = 0u;
    __syncthreads();

    // Phase A: batched row loads -> histogram atomics w/ rank capture.
    unsigned rr[KMAX], rk[KMAX];
    #pragma unroll
    for (int k = 0; k < KMAX; ++k) {
        int i = k * 256 + t;
        if (i < Cb) {
            int r = is64 ? (int)ll[s + i] : ii[s + i];
            rr[k] = (unsigned)min(max(r, 0), N - 1);
        } else rr[k] = 0xFFFFFFFFu;
    }
    #pragma unroll
    for (int k = 0; k < KMAX; ++k)
        if (rr[k] != 0xFFFFFFFFu)
            rk[k] = atomicAdd(&hist[w][rr[k] >> 9], 1u);
    if (t < NB) gb2[t] = localoff[(size_t)blk * NBP + t];
    __syncthreads();

    // merge + exclusive shfl-scan of 256 bins (hist[0]/hist[1] preserved)
    unsigned h = hist[0][t] + hist[1][t];
    unsigned x = h;
    #pragma unroll
    for (int off = 1; off < 64; off <<= 1) {
        unsigned y = (unsigned)__shfl_up((int)x, off, 64);
        if (lane >= off) x += y;
    }
    if (lane == 63) wt[wv] = x;
    __syncthreads();
    unsigned wadd = 0;
    for (int w2 = 0; w2 < wv; ++w2) wadd += wt[w2];
    unsigned ex = x + wadd - h;
    cur[t] = ex;
    __syncthreads();
    if (t < NB) gb2[t] -= cur[t];

    // Phase B: half-batched col+attr loads, then atomic-free staged writes.
    #pragma unroll
    for (int hb = 0; hb < 2; ++hb) {
        const int k0 = hb * HB;
        const int k1 = (hb == 0) ? HB : KMAX;
        int cc[HB]; float2 dd[HB];
        #pragma unroll
        for (int k = k0; k < k1; ++k) {
            int i = k * 256 + t;
            if (i < Cb) {
                int e = s + i;
                cc[k - k0] = is64 ? (int)ll[(long long)E + e] : ii[E + e];
                dd[k - k0] = eattr[e];
            }
        }
        #pragma unroll
        for (int k = k0; k < k1; ++k) {
            int i = k * 256 + t;
            if (i < Cb) {
                unsigned r = rr[k];
                unsigned b = r >> 9;
                unsigned rl = r & (NPB - 1);
                int c = min(max(cc[k - k0], 0), N - 1);
                unsigned slot = cur[b] + (w ? hist[0][b] : 0u) + rk[k];
                pl[slot] = make_uint2((unsigned)c | (rl << 17),
                                      packh2(dd[k - k0].x, dd[k - k0].y));
                bb[slot] = (unsigned char)b;
            }
        }
    }
    __syncthreads();

    // Phase C: half-batched staged reads -> coalesced global stores.
    #pragma unroll
    for (int hb = 0; hb < 2; ++hb) {
        const int k0 = hb * HB;
        const int k1 = (hb == 0) ? HB : KMAX;
        uint2 op[HB]; unsigned ob[HB];
        #pragma unroll
        for (int k = k0; k < k1; ++k) {
            int p = k * 256 + t;
            if (p < Cb) { op[k - k0] = pl[p]; ob[k - k0] = (unsigned)bb[p]; }
        }
        #pragma unroll
        for (int k = k0; k < k1; ++k) {
            int p = k * 256 + t;
            if (p < Cb) vals[gb2[ob[k - k0]] + (unsigned)p] = op[k - k0];
        }
    }
}

// Pass 4: gather + physics + in-LDS counting sort + register run-sum.
// INT histogram atomics only; fp32x4 pl staging (R9); raw v_rcp_f32 (R7).
__global__ __launch_bounds__(512) void accum_kernel(
    const uint2* __restrict__ vals, const unsigned* __restrict__ base,
    const float4* __restrict__ pred, int N,
    float* __restrict__ g /* [5][N] */, double* __restrict__ smooth_slots)
{
    __shared__ float4 pl[CH];          // 24 KB sorted fp32x4 physics
    __shared__ uint2 ph[NPB];          // 4 KB fp16 pred of bucket rows
    __shared__ unsigned hist[NPB];     // 2 KB
    __shared__ unsigned cur[NPB];      // 2 KB
    __shared__ unsigned wt[8];
    __shared__ double sm[8];

    const int b = blockIdx.x;
    const int t = threadIdx.x;
    const int wv = t >> 6, lane = t & 63;
    const int n0 = b * NPB;

    {   // stage bucket's pred rows as fp16
        int n = n0 + t;
        float4 p = (n < N) ? pred[n] : make_float4(0.f, 0.f, 0.f, 0.f);
        ph[t] = make_uint2(packh2(p.x, p.y), packh2(p.z, p.w));
    }

    unsigned s0 = base[b], e0 = base[b + 1];
    unsigned len = e0 - s0;
    unsigned s = s0 + (unsigned)(((unsigned long long)len * blockIdx.y) / SPLIT);
    unsigned e = s0 + (unsigned)(((unsigned long long)len * (blockIdx.y + 1)) / SPLIT);

    float cnt = 0, sdiv = 0, smx = 0, smy = 0, sstr = 0;
    double smooth = 0.0;

    for (unsigned cs = s; cs < e; cs += CH) {
        const int n = (int)min((unsigned)CH, e - cs);
        hist[t] = 0u;
        __syncthreads();

        uint2 vv[KACC]; unsigned rk2[KACC]; float4 pcc[KACC];
        #pragma unroll
        for (int k = 0; k < KACC; ++k) {
            int i = k * 512 + t;
            if (i < n) vv[k] = vals[cs + i];
            else vv[k].x = 0xFFFFFFFFu;
        }
        #pragma unroll
        for (int k = 0; k < KACC; ++k) {
            int i = k * 512 + t;
            if (i < n) {
                rk2[k] = atomicAdd(&hist[(vv[k].x >> 17) & (NPB - 1)], 1u);
                pcc[k] = pred[vv[k].x & 0x1FFFFu];
            }
        }
        __syncthreads();

        unsigned v = hist[t];
        unsigned x = v;
        #pragma unroll
        for (int off = 1; off < 64; off <<= 1) {
            unsigned y = (unsigned)__shfl_up((int)x, off, 64);
            if (lane >= off) x += y;
        }
        if (lane == 63) wt[wv] = x;
        __syncthreads();
        unsigned wadd = 0;
        for (int w = 0; w < wv; ++w) wadd += wt[w];
        unsigned incl = x + wadd;
        unsigned ex0 = incl - v;
        cur[t] = ex0;
        cnt += (float)v;
        __syncthreads();

        #pragma unroll
        for (int k = 0; k < KACC; ++k) {
            int i = k * 512 + t;
            if (i >= n) continue;
            unsigned pk = vv[k].x;
            unsigned rl = (pk >> 17) & (NPB - 1);
            float2 dxy = unpackh2(vv[k].y);
            float4 pc = pcc[k];
            uint2 pru = ph[rl];
            float2 pxy = unpackh2(pru.x);
            float2 pzw = unpackh2(pru.y);
            float du = pc.x - pxy.x, dv = pc.y - pxy.y;
            float dp = pc.z - pzw.x, dn = pc.w - pzw.y;
            float rx  = __builtin_amdgcn_rcpf(dxy.x + EPS);
            float ry  = __builtin_amdgcn_rcpf(dxy.y + EPS);
            float rx2 = __builtin_amdgcn_rcpf(dxy.x * dxy.x + EPS);
            float ry2 = __builtin_amdgcn_rcpf(dxy.y * dxy.y + EPS);
            float du_dx = du * rx, du_dy = du * ry;
            float dv_dx = dv * rx, dv_dy = dv * ry;
            float nu_eff = NU_MOL + pzw.y;
            float sh = du_dy + dv_dx;
            float div_e = du_dx + dv_dy;
            float mx_e  = dp * rx + nu_eff * du * rx2;
            float my_e  = dp * ry + nu_eff * dv * ry2;
            float str_e = 2.0f * (du_dx * du_dx + dv_dy * dv_dy) + sh * sh;
            pl[cur[rl] + rk2[k]] = make_float4(div_e, mx_e, my_e, str_e);
            smooth += (double)(du * du + dv * dv + dp * dp + dn * dn);
        }
        __syncthreads();

        for (unsigned i = ex0; i < incl; ++i) {
            float4 pv = pl[i];
            sdiv += pv.x;
            smx  += pv.y;
            smy  += pv.z;
            sstr += pv.w;
        }
        __syncthreads();
    }

    {
        int n = n0 + t;
        if (n < N) {
            atomicAdd(&g[0 * (size_t)N + n], cnt);
            atomicAdd(&g[1 * (size_t)N + n], sdiv);
            atomicAdd(&g[2 * (size_t)N + n], smx);
            atomicAdd(&g[3 * (size_t)N + n], smy);
            atomicAdd(&g[4 * (size_t)N + n], sstr);
        }
    }

    for (int off = 32; off > 0; off >>= 1)
        smooth += __shfl_down(smooth, off);
    if (lane == 0) sm[wv] = smooth;
    __syncthreads();
    if (t == 0) {
        double tot = 0;
        #pragma unroll
        for (int w = 0; w < 8; ++w) tot += sm[w];
        atomicAdd(&smooth_slots[(b * SPLIT + blockIdx.y) & 63], tot);
    }
}

// Pass 5: node losses from g[5][N].
__global__ __launch_bounds__(256) void node_final_kernel(
    const float* __restrict__ g, const float4* __restrict__ pred,
    const float4* __restrict__ tgt, const unsigned char* __restrict__ wall,
    int N, double* __restrict__ d)
{
    int i = blockIdx.x * 256 + threadIdx.x;
    double v0 = 0, v1 = 0, v2 = 0, v3 = 0, v4 = 0, v5 = 0, v6 = 0, v7 = 0;
    if (i < N) {
        float cnt = g[0 * (size_t)N + i];
        float inv = 1.0f / fmaxf(cnt, 1.0f);
        float div = g[1 * (size_t)N + i] * inv;
        float mx  = g[2 * (size_t)N + i] * inv;
        float my  = g[3 * (size_t)N + i] * inv;
        float sn  = g[4 * (size_t)N + i] * inv;
        float4 p = pred[i];
        float4 tg = tgt[i];
        float prod = p.w * sn;
        float m = wall[i] ? 1.0f : 0.0f;
        float e0 = p.x - tg.x, e1 = p.y - tg.y, e2 = p.z - tg.z, e3 = p.w - tg.w;
        float uv = p.x * p.x + p.y * p.y;
        v0 = (double)(e0 * e0 + e1 * e1 + e2 * e2 + e3 * e3);
        v1 = (double)div * (double)div;
        v2 = (double)mx * (double)mx + (double)my * (double)my;
        v3 = (double)prod * (double)prod;
        v4 = (double)p.w * (double)p.w;
        v5 = (double)m;
        v6 = (double)(m * uv);
        v7 = (double)(m * (uv + p.w * p.w));
    }
    for (int off = 32; off > 0; off >>= 1) {
        v0 += __shfl_down(v0, off); v1 += __shfl_down(v1, off);
        v2 += __shfl_down(v2, off); v3 += __shfl_down(v3, off);
        v4 += __shfl_down(v4, off); v5 += __shfl_down(v5, off);
        v6 += __shfl_down(v6, off); v7 += __shfl_down(v7, off);
    }
    __shared__ double sm[4][8];
    int lane = threadIdx.x & 63, wv = threadIdx.x >> 6;
    if (lane == 0) {
        sm[wv][0] = v0; sm[wv][1] = v1; sm[wv][2] = v2; sm[wv][3] = v3;
        sm[wv][4] = v4; sm[wv][5] = v5; sm[wv][6] = v6; sm[wv][7] = v7;
    }
    __syncthreads();
    if (threadIdx.x < 8) {
        int q = threadIdx.x;
        atomicAdd(&d[q], sm[0][q] + sm[1][q] + sm[2][q] + sm[3][q]);
    }
}

// ===================== fallback path (R1-style, known-correct) =====================

__global__ __launch_bounds__(256) void edge_kernel(
    const void* __restrict__ eidx, const float2* __restrict__ eattr,
    const float4* __restrict__ pred, int E, int N, const int* __restrict__ flag,
    float* __restrict__ a_cnt, float* __restrict__ a_div,
    float* __restrict__ a_mx, float* __restrict__ a_my,
    float* __restrict__ a_str, double* __restrict__ smooth_slots)
{
    const int is64 = *flag;
    const long long* ll = (const long long*)eidx;
    const int* ii = (const int*)eidx;
    double smooth = 0.0;
    const int stride = gridDim.x * blockDim.x;
    for (int e = blockIdx.x * blockDim.x + threadIdx.x; e < E; e += stride) {
        int row, col;
        if (is64) { row = (int)ll[e]; col = (int)ll[(long long)E + e]; }
        else      { row = ii[e];      col = ii[E + e]; }
        row = min(max(row, 0), N - 1);
        col = min(max(col, 0), N - 1);
        float2 dxy = eattr[e];
        float4 pr = pred[row];
        float4 pc = pred[col];
        float du = pc.x - pr.x, dv = pc.y - pr.y;
        float dp = pc.z - pr.z, dn = pc.w - pr.w;
        float rx  = 1.0f / (dxy.x + EPS);
        float ry  = 1.0f / (dxy.y + EPS);
        float rx2 = 1.0f / (dxy.x * dxy.x + EPS);
        float ry2 = 1.0f / (dxy.y * dxy.y + EPS);
        float du_dx = du * rx, du_dy = du * ry;
        float dv_dx = dv * rx, dv_dy = dv * ry;
        float nu_eff = NU_MOL + pr.w;
        atomicAdd(&a_cnt[row], 1.0f);
        atomicAdd(&a_div[row], du_dx + dv_dy);
        atomicAdd(&a_mx[row], dp * rx + nu_eff * du * rx2);
        atomicAdd(&a_my[row], dp * ry + nu_eff * dv * ry2);
        float sh = du_dy + dv_dx;
        atomicAdd(&a_str[row], 2.0f * (du_dx * du_dx + dv_dy * dv_dy) + sh * sh);
        smooth += (double)(du * du + dv * dv + dp * dp + dn * dn);
    }
    for (int off = 32; off > 0; off >>= 1)
        smooth += __shfl_down(smooth, off);
    __shared__ double sm[4];
    int lane = threadIdx.x & 63, wv = threadIdx.x >> 6;
    if (lane == 0) sm[wv] = smooth;
    __syncthreads();
    if (threadIdx.x == 0)
        atomicAdd(&smooth_slots[blockIdx.x & 63], sm[0] + sm[1] + sm[2] + sm[3]);
}

__global__ __launch_bounds__(256) void node_kernel(
    const float4* __restrict__ pred, const float4* __restrict__ tgt,
    const unsigned char* __restrict__ wall, int N,
    const float* __restrict__ a_cnt, const float* __restrict__ a_div,
    const float* __restrict__ a_mx, const float* __restrict__ a_my,
    const float* __restrict__ a_str, double* __restrict__ d)
{
    int i = blockIdx.x * blockDim.x + threadIdx.x;
    double v0 = 0, v1 = 0, v2 = 0, v3 = 0, v4 = 0, v5 = 0, v6 = 0, v7 = 0;
    if (i < N) {
        float4 p = pred[i];
        float4 t = tgt[i];
        float inv = 1.0f / fmaxf(a_cnt[i], 1.0f);
        float div = a_div[i] * inv;
        float mx = a_mx[i] * inv, my = a_my[i] * inv;
        float sn = a_str[i] * inv;
        float prod = p.w * sn;
        float m = wall[i] ? 1.0f : 0.0f;
        float e0 = p.x - t.x, e1 = p.y - t.y, e2 = p.z - t.z, e3 = p.w - t.w;
        float uv = p.x * p.x + p.y * p.y;
        v0 = (double)(e0 * e0 + e1 * e1 + e2 * e2 + e3 * e3);
        v1 = (double)div * (double)div;
        v2 = (double)mx * (double)mx + (double)my * (double)my;
        v3 = (double)prod * (double)prod;
        v4 = (double)p.w * (double)p.w;
        v5 = (double)m;
        v6 = (double)(m * uv);
        v7 = (double)(m * (uv + p.w * p.w));
    }
    for (int off = 32; off > 0; off >>= 1) {
        v0 += __shfl_down(v0, off); v1 += __shfl_down(v1, off);
        v2 += __shfl_down(v2, off); v3 += __shfl_down(v3, off);
        v4 += __shfl_down(v4, off); v5 += __shfl_down(v5, off);
        v6 += __shfl_down(v6, off); v7 += __shfl_down(v7, off);
    }
    __shared__ double sm[4][8];
    int lane = threadIdx.x & 63, wv = threadIdx.x >> 6;
    if (lane == 0) {
        sm[wv][0] = v0; sm[wv][1] = v1; sm[wv][2] = v2; sm[wv][3] = v3;
        sm[wv][4] = v4; sm[wv][5] = v5; sm[wv][6] = v6; sm[wv][7] = v7;
    }
    __syncthreads();
    if (threadIdx.x < 8) {
        int q = threadIdx.x;
        atomicAdd(&d[q], sm[0][q] + sm[1][q] + sm[2][q] + sm[3][q]);
    }
}

// ===================== launch =====================

extern "C" void kernel_launch(void* const* d_in, const int* in_sizes, int n_in,
                              void* d_out, int out_size, void* d_ws, size_t ws_size,
                              hipStream_t stream) {
    const float4* pred = (const float4*)d_in[0];
    const float4* tgt  = (const float4*)d_in[1];
    const float2* eattr = (const float2*)d_in[2];
    const void* eidx = d_in[3];
    const unsigned char* wall = (const unsigned char*)d_in[4];
    int N = in_sizes[0] / 4;
    int E = in_sizes[2] / 2;
    int NB = (N + NPB - 1) / NPB;
    int chunk = (E + NBLK - 1) / NBLK;
    int ntiles = (NB + 63) / 64;

    char* ws = (char*)d_ws;
    double* d = (double*)ws;                 // 8 scalars
    double* smooth_slots = d + 8;            // 64 slots
    int* flag = (int*)(ws + 576);

    size_t off = 1024;
    unsigned* gsum   = (unsigned*)(ws + off); off += (size_t)NGRP * NBP * 4; // zeroed
    size_t zbytes = off;                      // only header + gsum (~34KB)
    float* g        = (float*)(ws + off);     off += (size_t)5 * N * 4;  // zeroed by scanlocal
    unsigned* counts = (unsigned*)(ws + off); off += (size_t)NBLK * NBP * 4;
    unsigned* base   = (unsigned*)(ws + off); off += (size_t)(NB + 1) * 4;
    off = (off + 15) & ~(size_t)15;
    uint2* vals      = (uint2*)(ws + off);    off += (size_t)E * 8;
    size_t need_fast = off;

    bool fast = (NB <= MAXNB) && (N <= 131072) && (chunk <= CMAX) &&
                (ws_size >= need_fast);

    if (fast) {
        hipMemsetAsync(d_ws, 0, zbytes, stream);
        count_kernel<<<NBLK, 256, 0, stream>>>(eidx, E, N, NB, counts, gsum);
        scanlocal_kernel<<<dim3(NGRP, ntiles), 256, 0, stream>>>(counts, gsum,
                                                                 base, g, N, NB);
        scatter_kernel<<<NBLK, 256, 0, stream>>>(eidx, eattr, E, N, NB,
                                                 counts, vals);
        accum_kernel<<<dim3(NB, SPLIT), 512, 0, stream>>>(vals, base, pred, N,
                                                          g, smooth_slots);
        node_final_kernel<<<(N + 255) / 256, 256, 0, stream>>>(g, pred, tgt, wall,
                                                               N, d);
        finalize_kernel<<<1, 1, 0, stream>>>(d, smooth_slots, N, E, (float*)d_out);
    } else {
        float* arrays = (float*)(ws + 1024);
        float* a_cnt = arrays + (size_t)0 * N;
        float* a_div = arrays + (size_t)1 * N;
        float* a_mx  = arrays + (size_t)2 * N;
        float* a_my  = arrays + (size_t)3 * N;
        float* a_str = arrays + (size_t)4 * N;
        size_t zb = 1024 + (size_t)5 * N * sizeof(float);
        hipMemsetAsync(d_ws, 0, zb, stream);
        detect_idx_dtype<<<1, 1, 0, stream>>>(eidx, N, flag);
        edge_kernel<<<4096, 256, 0, stream>>>(eidx, eattr, pred, E, N, flag,
                                              a_cnt, a_div, a_mx, a_my, a_str,
                                              smooth_slots);
        node_kernel<<<(N + 255) / 256, 256, 0, stream>>>(pred, tgt, wall, N,
                                                         a_cnt, a_div, a_mx, a_my,
                                                         a_str, d);
        finalize_kernel<<<1, 1, 0, stream>>>(d, smooth_slots, N, E, (float*)d_out);
    }
}